// Round 4
// baseline (107634.973 us; speedup 1.0000x reference)
//
#include <hip/hip_runtime.h>
#include <hip/hip_bf16.h>
#include <math.h>

// DARQN: conv×3 -> per-step additive attention + LSTM scan (T=2048) -> q head.
// R4: XCD-local scan (runtime election via XCC_ID pigeonhole over 128 WGs),
// sc0 (L1-bypass, L2-resolved) transport, HARDENED: hybrid polls (sc0 fast
// path + periodic agent-scope authoritative load), all spins bounded, per-WG
// dead-latch so a timeout degrades to fast wrong-answer instead of a hang.

#define T_FRAMES 2048
#define NI 49
#define HID 256
#define NA 18
#define NWG 8
#define NLAUNCH 128

typedef __bf16 v8bf __attribute__((ext_vector_type(8)));
typedef float v4f __attribute__((ext_vector_type(4)));
typedef unsigned uint4v __attribute__((ext_vector_type(4)));

// ---------------- workspace layout (bytes) ----------------
static constexpr size_t OFF_FM1   = 0;                  // fm1 [2048,32,20,20] f32; reused for A [2048,49,256] f32
static constexpr size_t OFF_FM2   = 104857600;          // fm2 [2048,64,9,9] f32; reused for comm block
static constexpr size_t OFF_VECS  = 147324928;          // vecs [2048,49,256] f32
static constexpr size_t OFF_W2B   = 250085376;          // bf16 256*256
static constexpr size_t OFF_WIHB  = OFF_W2B  + 131072;  // bf16 1024*256
static constexpr size_t OFF_WHHB  = OFF_WIHB + 524288;  // bf16 1024*256
static constexpr size_t OFF_W1T   = OFF_WHHB + 524288;  // f32 256*256
// comm block aliases fm2 region (valid after conv3 consumed fm2):
static constexpr size_t OFF_HBUF  = OFF_FM2;            // f32[256] (one 128B line per WG slice)
static constexpr size_t OFF_CPUB  = OFF_FM2 + 1024;     // uint[16*256]; rows 8..15 permanent zeros
static constexpr size_t OFF_FLH   = OFF_FM2 + 17408;    // u32[8*32] (128B apart)
static constexpr size_t OFF_FLC   = OFF_FM2 + 18432;    // u32[8*32]
static constexpr size_t OFF_XCNT  = OFF_FM2 + 19456;    // u32[16]
static constexpr size_t OFF_WIN   = OFF_FM2 + 19520;    // u32

// ---------------- sc0 transport helpers (same-XCD L2-resolved) ----------------
__device__ __forceinline__ unsigned ld_flag(const unsigned* p) {
  unsigned v;
  asm volatile("global_load_dword %0, %1, off sc0\n\ts_waitcnt vmcnt(0)"
               : "=v"(v) : "v"(p) : "memory");
  return v;
}
__device__ __forceinline__ float ldf_sc0(const float* p) {
  float v;
  asm volatile("global_load_dword %0, %1, off sc0\n\ts_waitcnt vmcnt(0)"
               : "=v"(v) : "v"(p) : "memory");
  return v;
}
__device__ __forceinline__ void st_sc0(unsigned* p, unsigned v) {
  asm volatile("global_store_dword %0, %1, off sc0" :: "v"(p), "v"(v) : "memory");
}
__device__ __forceinline__ void stf_sc0(float* p, float v) {
  asm volatile("global_store_dword %0, %1, off sc0" :: "v"(p), "v"(v) : "memory");
}
__device__ __forceinline__ uint4v ld16_nw(const unsigned* p) {  // no wait: batch + vmcnt later
  uint4v v;
  asm volatile("global_load_dwordx4 %0, %1, off sc0" : "=v"(v) : "v"(p) : "memory");
  return v;
}
__device__ __forceinline__ void wait_vm0() {
  asm volatile("s_waitcnt vmcnt(0)" ::: "memory");
}

// Hybrid bounded poll: sc0 fast path, agent-scope authoritative load every 256
// iters, 4M-iteration bound, dead-latch. Returns 1 if target reached.
__device__ __forceinline__ int poll_flags(const unsigned* base, int lane, unsigned tgt, int* dead) {
  if (*dead) return 0;
  const unsigned* fp = base + ((lane < NWG) ? lane : (NWG - 1)) * 32;
  for (int guard = 0; guard < 4000000; ++guard) {
    unsigned fv;
    if ((guard & 255) == 255)
      fv = __hip_atomic_load(fp, __ATOMIC_ACQUIRE, __HIP_MEMORY_SCOPE_AGENT);
    else
      fv = ld_flag(fp);
    if (lane >= NWG) fv = tgt;
    if (__all(fv >= tgt)) return 1;
  }
  *dead = 1;
  return 0;
}

// ---------------- weight prep ----------------
__global__ void prep_weights(const float* __restrict__ w2, const float* __restrict__ wih,
                             const float* __restrict__ whh, const float* __restrict__ w1,
                             __bf16* w2b, __bf16* wihb, __bf16* whhb, float* w1t) {
  int idx = blockIdx.x * 256 + threadIdx.x;
  int stride = gridDim.x * 256;
  for (int i = idx; i < 65536; i += stride) w2b[i] = (__bf16)w2[i];
  for (int i = idx; i < 262144; i += stride) wihb[i] = (__bf16)wih[i];
  for (int i = idx; i < 262144; i += stride) whhb[i] = (__bf16)whh[i];
  for (int i = idx; i < 65536; i += stride) {
    int r = i >> 8, c = i & 255;
    w1t[c * 256 + r] = w1[i];
  }
}

// ---------------- conv1: [T,1,84,84] -> [T,32,20,20], k8 s4 ----------------
__global__ void conv1_k(const float* __restrict__ x, const float* __restrict__ w,
                        const float* __restrict__ b, float* __restrict__ y) {
  int idx = blockIdx.x * 256 + threadIdx.x;
  if (idx >= T_FRAMES * 32 * 20 * 20) return;
  int xx = idx % 20, yy = (idx / 20) % 20, o = (idx / 400) % 32, t = idx / 12800;
  const float* xp = x + t * 7056 + yy * 4 * 84 + xx * 4;
  const float* wp = w + o * 64;
  float acc = b[o];
  #pragma unroll
  for (int ky = 0; ky < 8; ky++)
    #pragma unroll
    for (int kx = 0; kx < 8; kx++)
      acc += xp[ky * 84 + kx] * wp[ky * 8 + kx];
  y[idx] = fmaxf(acc, 0.f);
}

// ---------------- conv2: [T,32,20,20] -> [T,64,9,9], k4 s2 ----------------
__global__ __launch_bounds__(256) void conv2_k(const float* __restrict__ fm1, const float* __restrict__ w,
                                               const float* __restrict__ b, float* __restrict__ fm2) {
  __shared__ float xs[32 * 400];
  int t = blockIdx.x, tid = threadIdx.x;
  for (int i = tid; i < 12800; i += 256) xs[i] = fm1[t * 12800 + i];
  __syncthreads();
  int o = tid >> 2, q = tid & 3;
  int p0 = q * 21, p1 = (p0 + 21 < 81) ? p0 + 21 : 81;
  int ob[21];
  #pragma unroll
  for (int i2 = 0; i2 < 21; i2++) {
    int p = p0 + i2; if (p > 80) p = 80;
    int yy = p / 9, xx2 = p - yy * 9;
    ob[i2] = yy * 40 + xx2 * 2;
  }
  float acc[21];
  #pragma unroll
  for (int i2 = 0; i2 < 21; i2++) acc[i2] = 0.f;
  for (int c = 0; c < 32; c++) {
    int cbase = c * 400;
    for (int ky = 0; ky < 4; ky++)
      for (int kx = 0; kx < 4; kx++) {
        float wgt = w[((o * 32 + c) * 4 + ky) * 4 + kx];
        int kyo = ky * 20 + kx;
        #pragma unroll
        for (int i2 = 0; i2 < 21; i2++)
          acc[i2] += wgt * xs[cbase + ob[i2] + kyo];
      }
  }
  float bo = b[o];
  #pragma unroll
  for (int i2 = 0; i2 < 21; i2++) {
    int p = p0 + i2;
    if (p < p1) fm2[t * 5184 + o * 81 + p] = fmaxf(acc[i2] + bo, 0.f);
  }
}

// ---------------- conv3: [T,64,9,9] -> vecs [T,49,256], k3 s1 ----------------
__global__ __launch_bounds__(256) void conv3_k(const float* __restrict__ fm2, const float* __restrict__ w,
                                               const float* __restrict__ b, float* __restrict__ vecs) {
  __shared__ float xs[64 * 81];
  __shared__ float ws4[256][37];
  int t = blockIdx.x, tid = threadIdx.x;
  for (int i = tid; i < 64 * 81; i += 256) xs[i] = fm2[t * 5184 + i];
  float acc[49];
  #pragma unroll
  for (int i = 0; i < 49; i++) acc[i] = 0.f;
  for (int c0 = 0; c0 < 64; c0 += 4) {
    __syncthreads();
    for (int i = tid; i < 256 * 36; i += 256) {
      int oo = i / 36, j = i - oo * 36;
      ws4[oo][j] = w[oo * 576 + c0 * 9 + j];
    }
    __syncthreads();
    for (int cc = 0; cc < 4; cc++)
      for (int ky = 0; ky < 3; ky++)
        for (int kx = 0; kx < 3; kx++) {
          float wgt = ws4[tid][cc * 9 + ky * 3 + kx];
          const float* xp = &xs[(c0 + cc) * 81 + ky * 9 + kx];
          #pragma unroll
          for (int yy = 0; yy < 7; yy++)
            #pragma unroll
            for (int xx = 0; xx < 7; xx++)
              acc[yy * 7 + xx] += wgt * xp[yy * 9 + xx];
        }
  }
  float bo = b[tid];
  for (int i = 0; i < 49; i++)
    vecs[(t * 49 + i) * 256 + tid] = fmaxf(acc[i] + bo, 0.f);
}

// ---------------- A[t,i,:] = vecs[t,i,:] @ W1^T + b1 ----------------
__global__ __launch_bounds__(256) void aprep_k(const float* __restrict__ vecs, const float* __restrict__ w1t,
                                               const float* __restrict__ b1, float* __restrict__ A) {
  __shared__ float vs[49][256];
  int t = blockIdx.x, tid = threadIdx.x;
  for (int i = tid; i < 49 * 256; i += 256) vs[i >> 8][i & 255] = vecs[t * 12544 + i];
  __syncthreads();
  float acc[49];
  #pragma unroll
  for (int i = 0; i < 49; i++) acc[i] = 0.f;
  for (int k = 0; k < 256; k++) {
    float wgt = w1t[k * 256 + tid];
    #pragma unroll
    for (int i = 0; i < 49; i++) acc[i] += vs[i][k] * wgt;
  }
  float bb = b1[tid];
  for (int i = 0; i < 49; i++) A[(t * 49 + i) * 256 + tid] = acc[i] + bb;
}

// ---------------- init comm (after conv3: aliases fm2) ----------------
__global__ void init_comm(unsigned* flh, unsigned* flc, unsigned* cpub,
                          unsigned* xcnt, unsigned* winner) {
  int idx = blockIdx.x * 256 + threadIdx.x;
  if (idx < NWG * 32) { flh[idx] = 0u; flc[idx] = 0u; }
  for (int i = idx; i < 8 * 256; i += gridDim.x * 256) cpub[8 * 256 + i] = 0u;
  if (idx < 16) xcnt[idx] = 0u;
  if (idx == 16) *winner = 0xFFFFFFFFu;
}

__device__ __forceinline__ float tanh_fast(float x) {
  float e = __expf(2.f * x);
  return 1.f - 2.f / (e + 1.f);
}

// ---------------- sequential scan: 8 same-XCD WGs, sc0 L2-local sync ----------------
__global__ __launch_bounds__(256, 1) void scan_k(
    const float* __restrict__ A, const float* __restrict__ vecs,
    const __bf16* __restrict__ w2b, const __bf16* __restrict__ wihb, const __bf16* __restrict__ whhb,
    const float* __restrict__ b2g, const float* __restrict__ bihg, const float* __restrict__ bhhg,
    const float* __restrict__ qw, const float* __restrict__ qb,
    float* hbuf, unsigned* cpub, unsigned* flh, unsigned* flc,
    unsigned* xcnt, unsigned* winner, float* out) {
  __shared__ __bf16 Ss[16][264];
  __shared__ float hs[HID];
  __shared__ __bf16 hbf[HID];
  __shared__ float Wt[8][HID];
  __shared__ float cxp[8][HID];
  __shared__ float b2s[HID];
  __shared__ float gb[4][32];
  __shared__ int role_s;

  const int tid = threadIdx.x;

  // ---- XCD election: first XCD to collect NWG workgroups wins (bounded) ----
  if (tid == 0) {
    unsigned xcc;
    asm volatile("s_getreg_b32 %0, hwreg(HW_REG_XCC_ID)" : "=s"(xcc));
    xcc &= 0xFu;
    unsigned r = atomicAdd(&xcnt[xcc], 1u);           // device-scope
    if (r == NWG - 1) atomicCAS(winner, 0xFFFFFFFFu, xcc);
    unsigned wsel = 0xFFFFFFFFu;
    for (int g = 0; g < 2000000; ++g) {               // bounded: ~0.5 s worst
      wsel = __hip_atomic_load(winner, __ATOMIC_ACQUIRE, __HIP_MEMORY_SCOPE_AGENT);
      if (wsel != 0xFFFFFFFFu) break;
      __builtin_amdgcn_s_sleep(4);
    }
    role_s = (wsel != 0xFFFFFFFFu && xcc == wsel && r < NWG) ? (int)r : -1;
  }
  __syncthreads();
  const int w = role_s;
  if (w < 0) return;  // losers exit; winners all share one XCD => one L2

  const int lane = tid & 63;
  const int wv = tid >> 6;          // wave 0..3 (= LSTM gate id)
  const int quad = lane >> 4;
  const int l15 = lane & 15;
  const int r0 = 6 * w;
  const int nr = (w < 7) ? 6 : 7;   // 7*6 + 7 = 49
  const int prow = tid >> 5;        // 0..7 staging row
  const int pcol = (tid & 31) * 8;  // 8 contiguous cols
  int dead = 0;                     // poll-timeout latch: degrade, don't hang

  for (int i = tid; i < 16 * 264; i += 256) (&Ss[0][0])[i] = (__bf16)0.f;
  for (int i = tid; i < 8 * HID; i += 256) (&cxp[0][0])[i] = 0.f;
  b2s[tid] = b2g[tid];
  hs[tid] = 0.f;
  hbf[tid] = (__bf16)0.f;
  float cbias[4];
  if (tid < 32) {
    #pragma unroll
    for (int g = 0; g < 4; g++) {
      int row = 256 * g + 32 * w + tid;
      cbias[g] = bihg[row] + bhhg[row];
    }
  }
  float creg = 0.f;

  // ---- register-resident MFMA B-fragments ----
  v8bf BW2[4][8];
  #pragma unroll
  for (int ntl = 0; ntl < 4; ntl++) {
    const int row = wv * 64 + ntl * 16 + l15;
    #pragma unroll
    for (int k = 0; k < 8; k++)
      BW2[ntl][k] = *(const v8bf*)(w2b + row * 256 + k * 32 + quad * 8);
  }
  v8bf BIH[2][8], BHH[2][8];
  #pragma unroll
  for (int nt = 0; nt < 2; nt++) {
    const int row = 256 * wv + 32 * w + nt * 16 + l15;
    #pragma unroll
    for (int k = 0; k < 8; k++) {
      BIH[nt][k] = *(const v8bf*)(wihb + row * 256 + k * 32 + quad * 8);
      BHH[nt][k] = *(const v8bf*)(whhb + row * 256 + k * 32 + quad * 8);
    }
  }
  __syncthreads();

  for (int t = 0; t < T_FRAMES; t++) {
    // issue this step's A/vecs loads (fly during the h wait)
    int rr = r0 + prow; if (rr > 48) rr = 48;
    const float* Ap = A + ((long)t * NI + rr) * HID + pcol;
    const float* Vp = vecs + ((long)t * NI + rr) * HID + pcol;
    const float4 a40 = *(const float4*)(Ap);
    const float4 a41 = *(const float4*)(Ap + 4);
    const float4 v40 = *(const float4*)(Vp);
    const float4 v41 = *(const float4*)(Vp + 4);

    if (t > 0) {  // wait for h_t (flag value t) via L2-local hybrid polls
      if (wv == 0) poll_flags(flh, lane, (unsigned)t, &dead);
      __syncthreads();  // B0
      float hv = ldf_sc0(hbuf + tid);
      hs[tid] = hv;
      hbf[tid] = (__bf16)hv;
      __syncthreads();  // B1
    }

    // stage s = tanh(A + h) as bf16 (rows >= nr stay zero)
    if (prow < nr) {
      const float* hp = &hs[pcol];
      v8bf sv;
      sv[0] = (__bf16)tanh_fast(a40.x + hp[0]);
      sv[1] = (__bf16)tanh_fast(a40.y + hp[1]);
      sv[2] = (__bf16)tanh_fast(a40.z + hp[2]);
      sv[3] = (__bf16)tanh_fast(a40.w + hp[3]);
      sv[4] = (__bf16)tanh_fast(a41.x + hp[4]);
      sv[5] = (__bf16)tanh_fast(a41.y + hp[5]);
      sv[6] = (__bf16)tanh_fast(a41.z + hp[6]);
      sv[7] = (__bf16)tanh_fast(a41.w + hp[7]);
      *(v8bf*)&Ss[prow][pcol] = sv;
    }
    __syncthreads();  // B2

    // logits = s @ W2^T + b2 (rows 0..7 valid)
    v4f acc[4];
    #pragma unroll
    for (int ntl = 0; ntl < 4; ntl++) acc[ntl] = (v4f){0.f, 0.f, 0.f, 0.f};
    #pragma unroll
    for (int k = 0; k < 8; k++) {
      const v8bf av = *(const v8bf*)&Ss[l15][k * 32 + quad * 8];
      #pragma unroll
      for (int ntl = 0; ntl < 4; ntl++)
        acc[ntl] = __builtin_amdgcn_mfma_f32_16x16x32_bf16(av, BW2[ntl][k], acc[ntl], 0, 0, 0);
    }
    if (quad < 2) {
      #pragma unroll
      for (int ntl = 0; ntl < 4; ntl++) {
        const int col = wv * 64 + ntl * 16 + l15;
        const float bb = b2s[col];
        #pragma unroll
        for (int reg = 0; reg < 4; reg++)
          Wt[quad * 4 + reg][col] = acc[ntl][reg] + bb;
      }
    }
    __syncthreads();  // B3

    // softmax + ctx products (row = prow)
    if (prow < nr) {
      float x[8];
      *(float4*)&x[0] = *(const float4*)&Wt[prow][pcol];
      *(float4*)&x[4] = *(const float4*)&Wt[prow][pcol + 4];
      float m = x[0];
      #pragma unroll
      for (int i = 1; i < 8; i++) m = fmaxf(m, x[i]);
      #pragma unroll
      for (int off = 16; off; off >>= 1) m = fmaxf(m, __shfl_xor(m, off, 64));
      float e[8], sm = 0.f;
      #pragma unroll
      for (int i = 0; i < 8; i++) { e[i] = __expf(x[i] - m); sm += e[i]; }
      #pragma unroll
      for (int off = 16; off; off >>= 1) sm += __shfl_xor(sm, off, 64);
      const float inv = 1.f / sm;
      cxp[prow][pcol + 0] = e[0] * inv * v40.x;
      cxp[prow][pcol + 1] = e[1] * inv * v40.y;
      cxp[prow][pcol + 2] = e[2] * inv * v40.z;
      cxp[prow][pcol + 3] = e[3] * inv * v40.w;
      cxp[prow][pcol + 4] = e[4] * inv * v41.x;
      cxp[prow][pcol + 5] = e[5] * inv * v41.y;
      cxp[prow][pcol + 6] = e[6] * inv * v41.z;
      cxp[prow][pcol + 7] = e[7] * inv * v41.w;
    }
    __syncthreads();  // B5

    // channel sum of my rows -> bf16 pack -> publish via sc0 stores
    float cp = 0.f;
    #pragma unroll
    for (int r = 0; r < 8; r++) cp += cxp[r][tid];
    float cpo = __shfl_xor(cp, 1, 64);
    if ((tid & 1) == 0) {
      union { __bf16 b; unsigned short s; } lo, hi;
      lo.b = (__bf16)cp; hi.b = (__bf16)cpo;
      unsigned u = ((unsigned)hi.s << 16) | (unsigned)lo.s;
      st_sc0(&cpub[w * 256 + (tid >> 1)], u);
    }
    wait_vm0();       // my stores ack'd in L2
    __syncthreads();  // B6: all threads' stores ack'd
    if (tid == 0) st_sc0(&flc[w * 32], (unsigned)(t + 1));

    // h @ Whh^T chain (h known since step top) — overlaps the ctx wait
    v4f gacc[2];
    gacc[0] = (v4f){0.f, 0.f, 0.f, 0.f};
    gacc[1] = (v4f){0.f, 0.f, 0.f, 0.f};
    #pragma unroll
    for (int k = 0; k < 8; k++) {
      v8bf hf;
      #pragma unroll
      for (int z = 0; z < 8; z++) hf[z] = (__bf16)0.f;
      if (l15 == 0) hf = *(const v8bf*)&hbf[k * 32 + quad * 8];
      gacc[0] = __builtin_amdgcn_mfma_f32_16x16x32_bf16(hf, BHH[0][k], gacc[0], 0, 0, 0);
      gacc[1] = __builtin_amdgcn_mfma_f32_16x16x32_bf16(hf, BHH[1][k], gacc[1], 0, 0, 0);
    }

    // wait for all ctx flags (every wave polls, bounded + dead-latch)
    poll_flags(flc, lane, (unsigned)(t + 1), &dead);

    // gather P rows (bf16 ctx partials; rows 8..15 are permanent zeros)
    uint4v pr[8];
    const unsigned* gbase = cpub + l15 * 256 + quad * 4;
    #pragma unroll
    for (int k = 0; k < 8; k++) pr[k] = ld16_nw(gbase + k * 16);
    asm volatile("s_waitcnt vmcnt(0)"
                 : "+v"(pr[0]), "+v"(pr[1]), "+v"(pr[2]), "+v"(pr[3]),
                   "+v"(pr[4]), "+v"(pr[5]), "+v"(pr[6]), "+v"(pr[7]) :: "memory");
    #pragma unroll
    for (int k = 0; k < 8; k++) {
      union { uint4v u; v8bf v; } pf;
      pf.u = pr[k];
      gacc[0] = __builtin_amdgcn_mfma_f32_16x16x32_bf16(pf.v, BIH[0][k], gacc[0], 0, 0, 0);
      gacc[1] = __builtin_amdgcn_mfma_f32_16x16x32_bf16(pf.v, BIH[1][k], gacc[1], 0, 0, 0);
    }
    // reduce over P rows (D rows = quad*4+reg) -> per-col gate pre-activation
    #pragma unroll
    for (int nt = 0; nt < 2; nt++) {
      float tot = gacc[nt][0] + gacc[nt][1] + gacc[nt][2] + gacc[nt][3];
      tot += __shfl_xor(tot, 16, 64);
      tot += __shfl_xor(tot, 32, 64);
      if (lane < 16) gb[wv][nt * 16 + lane] = tot;
    }
    __syncthreads();  // B7

    // cell update; publish h slice via sc0
    if (tid < 32) {
      float gi = gb[0][tid] + cbias[0];
      float gf = gb[1][tid] + cbias[1];
      float gg = gb[2][tid] + cbias[2];
      float go = gb[3][tid] + cbias[3];
      float si = 1.f / (1.f + __expf(-gi));
      float sf = 1.f / (1.f + __expf(-gf));
      float so = 1.f / (1.f + __expf(-go));
      creg = sf * creg + si * tanh_fast(gg);
      float hn = so * tanh_fast(creg);
      stf_sc0(hbuf + 32 * w + tid, hn);
    }
    wait_vm0();
    __syncthreads();  // B8
    if (tid == 0) st_sc0(&flh[w * 32], (unsigned)(t + 1));
  }

  // q = h_T @ q_w^T + q_b
  if (w == 0) {
    if (wv == 0) poll_flags(flh, lane, (unsigned)T_FRAMES, &dead);
    __syncthreads();
    hs[tid] = ldf_sc0(hbuf + tid);
    __syncthreads();
    if (tid < NA) {
      float acc = qb[tid];
      for (int k = 0; k < HID; k++) acc += hs[k] * qw[tid * HID + k];
      out[tid] = acc;
    }
  }
}

extern "C" void kernel_launch(void* const* d_in, const int* in_sizes, int n_in,
                              void* d_out, int out_size, void* d_ws, size_t ws_size,
                              hipStream_t stream) {
  const float* frames = (const float*)d_in[0];
  const float* c1w = (const float*)d_in[1];
  const float* c1b = (const float*)d_in[2];
  const float* c2w = (const float*)d_in[3];
  const float* c2b = (const float*)d_in[4];
  const float* c3w = (const float*)d_in[5];
  const float* c3b = (const float*)d_in[6];
  const float* aw1 = (const float*)d_in[7];
  const float* ab1 = (const float*)d_in[8];
  const float* aw2 = (const float*)d_in[9];
  const float* ab2 = (const float*)d_in[10];
  const float* wih = (const float*)d_in[11];
  const float* whh = (const float*)d_in[12];
  const float* bih = (const float*)d_in[13];
  const float* bhh = (const float*)d_in[14];
  const float* qw  = (const float*)d_in[15];
  const float* qb  = (const float*)d_in[16];

  char* ws = (char*)d_ws;
  float*  fm1   = (float*)(ws + OFF_FM1);
  float*  A     = (float*)(ws + OFF_FM1);   // alias: fm1 dead after conv2
  float*  fm2   = (float*)(ws + OFF_FM2);
  float*  vecs  = (float*)(ws + OFF_VECS);
  __bf16* w2b   = (__bf16*)(ws + OFF_W2B);
  __bf16* wihb  = (__bf16*)(ws + OFF_WIHB);
  __bf16* whhb  = (__bf16*)(ws + OFF_WHHB);
  float*  w1t   = (float*)(ws + OFF_W1T);
  float*    hbuf   = (float*)(ws + OFF_HBUF);   // aliases fm2 (dead after conv3)
  unsigned* cpub   = (unsigned*)(ws + OFF_CPUB);
  unsigned* flh    = (unsigned*)(ws + OFF_FLH);
  unsigned* flc    = (unsigned*)(ws + OFF_FLC);
  unsigned* xcnt   = (unsigned*)(ws + OFF_XCNT);
  unsigned* winner = (unsigned*)(ws + OFF_WIN);

  prep_weights<<<256, 256, 0, stream>>>(aw2, wih, whh, aw1, w2b, wihb, whhb, w1t);
  conv1_k<<<102400, 256, 0, stream>>>(frames, c1w, c1b, fm1);
  conv2_k<<<T_FRAMES, 256, 0, stream>>>(fm1, c2w, c2b, fm2);
  conv3_k<<<T_FRAMES, 256, 0, stream>>>(fm2, c3w, c3b, vecs);
  aprep_k<<<T_FRAMES, 256, 0, stream>>>(vecs, w1t, ab1, A);
  init_comm<<<11, 256, 0, stream>>>(flh, flc, cpub, xcnt, winner);  // after conv3: comm aliases fm2
  scan_k<<<NLAUNCH, 256, 0, stream>>>(A, vecs, w2b, wihb, whhb, ab2, bih, bhh, qw, qb,
                                      hbuf, cpub, flh, flc, xcnt, winner, (float*)d_out);
}

// Round 5
// 19955.064 us; speedup vs baseline: 5.3939x; 5.3939x over previous
//
#include <hip/hip_runtime.h>
#include <hip/hip_bf16.h>
#include <math.h>

// DARQN: conv×3 -> per-step additive attention + LSTM scan (T=2048) -> q head.
// R5: scan transport = "tagged pairs": every published datum is an 8-byte
// (payload, step-tag) unit stored/loaded with relaxed agent-scope atomics.
// Kills the ack-before-flag wait AND the dependent post-detect gather of R2.
// 8 persistent WGs, single-slot buffers (inductively race-free), bounded polls.

#define T_FRAMES 2048
#define NI 49
#define HID 256
#define NA 18
#define NWG 8
#define POLL_MAX 1000000

typedef __bf16 v8bf __attribute__((ext_vector_type(8)));
typedef float v4f __attribute__((ext_vector_type(4)));
typedef unsigned long long u64;

// ---------------- workspace layout (bytes) ----------------
static constexpr size_t OFF_FM1   = 0;                  // fm1 [2048,32,20,20] f32; reused for A [2048,49,256] f32
static constexpr size_t OFF_FM2   = 104857600;          // fm2 [2048,64,9,9] f32; reused for comm block
static constexpr size_t OFF_VECS  = 147324928;          // vecs [2048,49,256] f32
static constexpr size_t OFF_W2B   = 250085376;          // bf16 256*256
static constexpr size_t OFF_WIHB  = OFF_W2B  + 131072;  // bf16 1024*256
static constexpr size_t OFF_WHHB  = OFF_WIHB + 524288;  // bf16 1024*256
static constexpr size_t OFF_W1T   = OFF_WHHB + 524288;  // f32 256*256
// comm block aliases fm2 region (valid after conv3 consumed fm2):
static constexpr size_t OFF_HPUB  = OFF_FM2;            // u64[256]  (f32 h | tag)
static constexpr size_t OFF_CPUB  = OFF_FM2 + 2048;     // u64[8*128] (2xbf16 | tag)

__device__ __forceinline__ u64 ld_pair(const u64* p) {
  return __hip_atomic_load(p, __ATOMIC_RELAXED, __HIP_MEMORY_SCOPE_AGENT);
}
__device__ __forceinline__ void st_pair(u64* p, u64 v) {
  __hip_atomic_store(p, v, __ATOMIC_RELAXED, __HIP_MEMORY_SCOPE_AGENT);
}

// ---------------- weight prep ----------------
__global__ void prep_weights(const float* __restrict__ w2, const float* __restrict__ wih,
                             const float* __restrict__ whh, const float* __restrict__ w1,
                             __bf16* w2b, __bf16* wihb, __bf16* whhb, float* w1t) {
  int idx = blockIdx.x * 256 + threadIdx.x;
  int stride = gridDim.x * 256;
  for (int i = idx; i < 65536; i += stride) w2b[i] = (__bf16)w2[i];
  for (int i = idx; i < 262144; i += stride) wihb[i] = (__bf16)wih[i];
  for (int i = idx; i < 262144; i += stride) whhb[i] = (__bf16)whh[i];
  for (int i = idx; i < 65536; i += stride) {
    int r = i >> 8, c = i & 255;
    w1t[c * 256 + r] = w1[i];
  }
}

// ---------------- conv1: [T,1,84,84] -> [T,32,20,20], k8 s4 ----------------
__global__ void conv1_k(const float* __restrict__ x, const float* __restrict__ w,
                        const float* __restrict__ b, float* __restrict__ y) {
  int idx = blockIdx.x * 256 + threadIdx.x;
  if (idx >= T_FRAMES * 32 * 20 * 20) return;
  int xx = idx % 20, yy = (idx / 20) % 20, o = (idx / 400) % 32, t = idx / 12800;
  const float* xp = x + t * 7056 + yy * 4 * 84 + xx * 4;
  const float* wp = w + o * 64;
  float acc = b[o];
  #pragma unroll
  for (int ky = 0; ky < 8; ky++)
    #pragma unroll
    for (int kx = 0; kx < 8; kx++)
      acc += xp[ky * 84 + kx] * wp[ky * 8 + kx];
  y[idx] = fmaxf(acc, 0.f);
}

// ---------------- conv2: [T,32,20,20] -> [T,64,9,9], k4 s2 ----------------
__global__ __launch_bounds__(256) void conv2_k(const float* __restrict__ fm1, const float* __restrict__ w,
                                               const float* __restrict__ b, float* __restrict__ fm2) {
  __shared__ float xs[32 * 400];
  int t = blockIdx.x, tid = threadIdx.x;
  for (int i = tid; i < 12800; i += 256) xs[i] = fm1[t * 12800 + i];
  __syncthreads();
  int o = tid >> 2, q = tid & 3;
  int p0 = q * 21, p1 = (p0 + 21 < 81) ? p0 + 21 : 81;
  int ob[21];
  #pragma unroll
  for (int i2 = 0; i2 < 21; i2++) {
    int p = p0 + i2; if (p > 80) p = 80;
    int yy = p / 9, xx2 = p - yy * 9;
    ob[i2] = yy * 40 + xx2 * 2;
  }
  float acc[21];
  #pragma unroll
  for (int i2 = 0; i2 < 21; i2++) acc[i2] = 0.f;
  for (int c = 0; c < 32; c++) {
    int cbase = c * 400;
    for (int ky = 0; ky < 4; ky++)
      for (int kx = 0; kx < 4; kx++) {
        float wgt = w[((o * 32 + c) * 4 + ky) * 4 + kx];
        int kyo = ky * 20 + kx;
        #pragma unroll
        for (int i2 = 0; i2 < 21; i2++)
          acc[i2] += wgt * xs[cbase + ob[i2] + kyo];
      }
  }
  float bo = b[o];
  #pragma unroll
  for (int i2 = 0; i2 < 21; i2++) {
    int p = p0 + i2;
    if (p < p1) fm2[t * 5184 + o * 81 + p] = fmaxf(acc[i2] + bo, 0.f);
  }
}

// ---------------- conv3: [T,64,9,9] -> vecs [T,49,256], k3 s1 ----------------
__global__ __launch_bounds__(256) void conv3_k(const float* __restrict__ fm2, const float* __restrict__ w,
                                               const float* __restrict__ b, float* __restrict__ vecs) {
  __shared__ float xs[64 * 81];
  __shared__ float ws4[256][37];
  int t = blockIdx.x, tid = threadIdx.x;
  for (int i = tid; i < 64 * 81; i += 256) xs[i] = fm2[t * 5184 + i];
  float acc[49];
  #pragma unroll
  for (int i = 0; i < 49; i++) acc[i] = 0.f;
  for (int c0 = 0; c0 < 64; c0 += 4) {
    __syncthreads();
    for (int i = tid; i < 256 * 36; i += 256) {
      int oo = i / 36, j = i - oo * 36;
      ws4[oo][j] = w[oo * 576 + c0 * 9 + j];
    }
    __syncthreads();
    for (int cc = 0; cc < 4; cc++)
      for (int ky = 0; ky < 3; ky++)
        for (int kx = 0; kx < 3; kx++) {
          float wgt = ws4[tid][cc * 9 + ky * 3 + kx];
          const float* xp = &xs[(c0 + cc) * 81 + ky * 9 + kx];
          #pragma unroll
          for (int yy = 0; yy < 7; yy++)
            #pragma unroll
            for (int xx = 0; xx < 7; xx++)
              acc[yy * 7 + xx] += wgt * xp[yy * 9 + xx];
        }
  }
  float bo = b[tid];
  for (int i = 0; i < 49; i++)
    vecs[(t * 49 + i) * 256 + tid] = fmaxf(acc[i] + bo, 0.f);
}

// ---------------- A[t,i,:] = vecs[t,i,:] @ W1^T + b1 ----------------
__global__ __launch_bounds__(256) void aprep_k(const float* __restrict__ vecs, const float* __restrict__ w1t,
                                               const float* __restrict__ b1, float* __restrict__ A) {
  __shared__ float vs[49][256];
  int t = blockIdx.x, tid = threadIdx.x;
  for (int i = tid; i < 49 * 256; i += 256) vs[i >> 8][i & 255] = vecs[t * 12544 + i];
  __syncthreads();
  float acc[49];
  #pragma unroll
  for (int i = 0; i < 49; i++) acc[i] = 0.f;
  for (int k = 0; k < 256; k++) {
    float wgt = w1t[k * 256 + tid];
    #pragma unroll
    for (int i = 0; i < 49; i++) acc[i] += vs[i][k] * wgt;
  }
  float bb = b1[tid];
  for (int i = 0; i < 49; i++) A[(t * 49 + i) * 256 + tid] = acc[i] + bb;
}

// ---------------- init comm (after conv3: aliases fm2) ----------------
__global__ void init_comm(u64* hpub, u64* cpub) {
  int idx = blockIdx.x * 256 + threadIdx.x;
  if (idx < 256) hpub[idx] = 0ull;
  if (idx < NWG * 128) cpub[idx] = 0ull;
}

__device__ __forceinline__ float tanh_fast(float x) {
  float e = __expf(2.f * x);
  return 1.f - 2.f / (e + 1.f);
}

// ---------------- sequential scan: 8 WGs, tagged-pair transport ----------------
__global__ __launch_bounds__(256, 1) void scan_k(
    const float* __restrict__ A, const float* __restrict__ vecs,
    const __bf16* __restrict__ w2b, const __bf16* __restrict__ wihb, const __bf16* __restrict__ whhb,
    const float* __restrict__ b2g, const float* __restrict__ bihg, const float* __restrict__ bhhg,
    const float* __restrict__ qw, const float* __restrict__ qb,
    u64* hpub, u64* cpub, float* out) {
  __shared__ __bf16 Ss[16][264];   // s rows bf16, padded
  __shared__ __bf16 hbf[HID];      // bf16 h for the Whh A-frag
  __shared__ float Wt[8][HID];     // logits / softmax rows
  __shared__ float cxp[8][HID];    // per-row ctx products
  __shared__ float b2s[HID];
  __shared__ float gb[4][32];
  __shared__ float hsf[HID];       // final h for q head

  const int w = blockIdx.x;
  const int tid = threadIdx.x;
  const int lane = tid & 63;
  const int wv = tid >> 6;          // wave 0..3 (= LSTM gate id)
  const int quad = lane >> 4;
  const int l15 = lane & 15;
  const int r0 = 6 * w;
  const int nr = (w < 7) ? 6 : 7;   // 7*6 + 7 = 49
  const int prow = tid >> 5;        // 0..7 staging row
  const int pcol = (tid & 31) * 8;  // 8 contiguous cols
  int dead = 0;                     // poll-timeout latch: degrade, don't hang

  for (int i = tid; i < 16 * 264; i += 256) (&Ss[0][0])[i] = (__bf16)0.f;
  for (int i = tid; i < 8 * HID; i += 256) (&cxp[0][0])[i] = 0.f;
  b2s[tid] = b2g[tid];
  hbf[tid] = (__bf16)0.f;
  float cbias[4];
  if (tid < 32) {
    #pragma unroll
    for (int g = 0; g < 4; g++) {
      int row = 256 * g + 32 * w + tid;
      cbias[g] = bihg[row] + bhhg[row];
    }
  }
  float creg = 0.f;  // cell state: tid<32 owns dim 32*w+tid

  // ---- register-resident MFMA B-fragments ----
  v8bf BW2[4][8];  // attention: wave wv owns logit cols wv*64 + ntl*16 + l15
  #pragma unroll
  for (int ntl = 0; ntl < 4; ntl++) {
    const int row = wv * 64 + ntl * 16 + l15;
    #pragma unroll
    for (int k = 0; k < 8; k++)
      BW2[ntl][k] = *(const v8bf*)(w2b + row * 256 + k * 32 + quad * 8);
  }
  v8bf BIH[2][8], BHH[2][8];  // LSTM: gate wv, dims 32*w + nt*16 + l15
  #pragma unroll
  for (int nt = 0; nt < 2; nt++) {
    const int row = 256 * wv + 32 * w + nt * 16 + l15;
    #pragma unroll
    for (int k = 0; k < 8; k++) {
      BIH[nt][k] = *(const v8bf*)(wihb + row * 256 + k * 32 + quad * 8);
      BHH[nt][k] = *(const v8bf*)(whhb + row * 256 + k * 32 + quad * 8);
    }
  }
  __syncthreads();

  for (int t = 0; t < T_FRAMES; t++) {
    // issue this step's A/vecs loads (fly during the h wait)
    int rr = r0 + prow; if (rr > 48) rr = 48;
    const float* Ap = A + ((long)t * NI + rr) * HID + pcol;
    const float* Vp = vecs + ((long)t * NI + rr) * HID + pcol;
    const float4 a40 = *(const float4*)(Ap);
    const float4 a41 = *(const float4*)(Ap + 4);
    const float4 v40 = *(const float4*)(Vp);
    const float4 v41 = *(const float4*)(Vp + 4);

    // ---- wait for h_t: poll tagged pairs, payload arrives WITH detection ----
    float hreg[8];
    #pragma unroll
    for (int i = 0; i < 8; i++) hreg[i] = 0.f;
    if (t > 0) {
      const unsigned tgt = (unsigned)t;
      const u64* hp = hpub + pcol;
      u64 v[8], vo = 0;
      #pragma unroll
      for (int i = 0; i < 8; i++) v[i] = 0;
      if (!dead) {
        for (int guard = 0;; ++guard) {
          #pragma unroll
          for (int i = 0; i < 8; i++) v[i] = ld_pair(hp + i);
          vo = ld_pair(hpub + tid);
          unsigned ok = (unsigned)(vo >> 32) == tgt;
          #pragma unroll
          for (int i = 0; i < 8; i++) ok &= ((unsigned)(v[i] >> 32) == tgt);
          if (__all(ok)) break;
          if (guard >= POLL_MAX) { dead = 1; break; }
        }
      }
      #pragma unroll
      for (int i = 0; i < 8; i++) hreg[i] = __uint_as_float((unsigned)v[i]);
      hbf[tid] = (__bf16)__uint_as_float((unsigned)vo);
    }

    // stage s = tanh(A + h) as bf16 (rows >= nr stay zero)
    if (prow < nr) {
      v8bf sv;
      sv[0] = (__bf16)tanh_fast(a40.x + hreg[0]);
      sv[1] = (__bf16)tanh_fast(a40.y + hreg[1]);
      sv[2] = (__bf16)tanh_fast(a40.z + hreg[2]);
      sv[3] = (__bf16)tanh_fast(a40.w + hreg[3]);
      sv[4] = (__bf16)tanh_fast(a41.x + hreg[4]);
      sv[5] = (__bf16)tanh_fast(a41.y + hreg[5]);
      sv[6] = (__bf16)tanh_fast(a41.z + hreg[6]);
      sv[7] = (__bf16)tanh_fast(a41.w + hreg[7]);
      *(v8bf*)&Ss[prow][pcol] = sv;
    }
    __syncthreads();  // B2: Ss + hbf visible

    // logits = s @ W2^T + b2 (rows 0..7 valid)
    v4f acc[4];
    #pragma unroll
    for (int ntl = 0; ntl < 4; ntl++) acc[ntl] = (v4f){0.f, 0.f, 0.f, 0.f};
    #pragma unroll
    for (int k = 0; k < 8; k++) {
      const v8bf av = *(const v8bf*)&Ss[l15][k * 32 + quad * 8];
      #pragma unroll
      for (int ntl = 0; ntl < 4; ntl++)
        acc[ntl] = __builtin_amdgcn_mfma_f32_16x16x32_bf16(av, BW2[ntl][k], acc[ntl], 0, 0, 0);
    }
    if (quad < 2) {
      #pragma unroll
      for (int ntl = 0; ntl < 4; ntl++) {
        const int col = wv * 64 + ntl * 16 + l15;
        const float bb = b2s[col];
        #pragma unroll
        for (int reg = 0; reg < 4; reg++)
          Wt[quad * 4 + reg][col] = acc[ntl][reg] + bb;
      }
    }
    __syncthreads();  // B3

    // softmax + ctx products (row = prow)
    if (prow < nr) {
      float x[8];
      *(float4*)&x[0] = *(const float4*)&Wt[prow][pcol];
      *(float4*)&x[4] = *(const float4*)&Wt[prow][pcol + 4];
      float m = x[0];
      #pragma unroll
      for (int i = 1; i < 8; i++) m = fmaxf(m, x[i]);
      #pragma unroll
      for (int off = 16; off; off >>= 1) m = fmaxf(m, __shfl_xor(m, off, 64));
      float e[8], sm = 0.f;
      #pragma unroll
      for (int i = 0; i < 8; i++) { e[i] = __expf(x[i] - m); sm += e[i]; }
      #pragma unroll
      for (int off = 16; off; off >>= 1) sm += __shfl_xor(sm, off, 64);
      const float inv = 1.f / sm;
      cxp[prow][pcol + 0] = e[0] * inv * v40.x;
      cxp[prow][pcol + 1] = e[1] * inv * v40.y;
      cxp[prow][pcol + 2] = e[2] * inv * v40.z;
      cxp[prow][pcol + 3] = e[3] * inv * v40.w;
      cxp[prow][pcol + 4] = e[4] * inv * v41.x;
      cxp[prow][pcol + 5] = e[5] * inv * v41.y;
      cxp[prow][pcol + 6] = e[6] * inv * v41.z;
      cxp[prow][pcol + 7] = e[7] * inv * v41.w;
    }
    __syncthreads();  // B5

    // channel sum of my rows -> tagged pair publish (no ack, no barrier)
    float cp = 0.f;
    #pragma unroll
    for (int r = 0; r < 8; r++) cp += cxp[r][tid];
    float cpo = __shfl_xor(cp, 1, 64);
    if ((tid & 1) == 0) {
      union { __bf16 b; unsigned short s; } lo, hi;
      lo.b = (__bf16)cp; hi.b = (__bf16)cpo;
      unsigned dat = ((unsigned)hi.s << 16) | (unsigned)lo.s;
      u64 pv = ((u64)(unsigned)(t + 1) << 32) | (u64)dat;
      st_pair(&cpub[w * 128 + (tid >> 1)], pv);
    }

    // h @ Whh^T chain (overlaps cpart flight)
    v4f gacc[2];
    gacc[0] = (v4f){0.f, 0.f, 0.f, 0.f};
    gacc[1] = (v4f){0.f, 0.f, 0.f, 0.f};
    #pragma unroll
    for (int k = 0; k < 8; k++) {
      v8bf hf;
      #pragma unroll
      for (int z = 0; z < 8; z++) hf[z] = (__bf16)0.f;
      if (l15 == 0) hf = *(const v8bf*)&hbf[k * 32 + quad * 8];
      gacc[0] = __builtin_amdgcn_mfma_f32_16x16x32_bf16(hf, BHH[0][k], gacc[0], 0, 0, 0);
      gacc[1] = __builtin_amdgcn_mfma_f32_16x16x32_bf16(hf, BHH[1][k], gacc[1], 0, 0, 0);
    }

    // ---- poll ALL ctx pairs straight into MFMA A-frag registers ----
    {
      const unsigned tgt2 = (unsigned)(t + 1);
      const u64* cb = cpub + (l15 & 7) * 128 + quad * 4;  // rows 8..15 masked below
      u64 cv[32];
      #pragma unroll
      for (int i = 0; i < 32; i++) cv[i] = 0;
      if (!dead) {
        for (int guard = 0;; ++guard) {
          #pragma unroll
          for (int k = 0; k < 8; k++)
            #pragma unroll
            for (int i = 0; i < 4; i++)
              cv[k * 4 + i] = ld_pair(cb + k * 16 + i);
          unsigned ok = 1;
          #pragma unroll
          for (int i = 0; i < 32; i++) ok &= ((unsigned)(cv[i] >> 32) == tgt2);
          if (__all(ok)) break;
          if (guard >= POLL_MAX) { dead = 1; break; }
        }
      }
      const bool zrow = (l15 >= 8);
      #pragma unroll
      for (int k = 0; k < 8; k++) {
        union { unsigned u[4]; v8bf v; } pf;
        #pragma unroll
        for (int i = 0; i < 4; i++)
          pf.u[i] = zrow ? 0u : (unsigned)cv[k * 4 + i];
        gacc[0] = __builtin_amdgcn_mfma_f32_16x16x32_bf16(pf.v, BIH[0][k], gacc[0], 0, 0, 0);
        gacc[1] = __builtin_amdgcn_mfma_f32_16x16x32_bf16(pf.v, BIH[1][k], gacc[1], 0, 0, 0);
      }
    }
    // reduce over P rows (D rows = quad*4+reg) -> per-col gate pre-activation
    #pragma unroll
    for (int nt = 0; nt < 2; nt++) {
      float tot = gacc[nt][0] + gacc[nt][1] + gacc[nt][2] + gacc[nt][3];
      tot += __shfl_xor(tot, 16, 64);
      tot += __shfl_xor(tot, 32, 64);
      if (lane < 16) gb[wv][nt * 16 + lane] = tot;
    }
    __syncthreads();  // B7

    // cell update; publish h slice as tagged pairs (no ack, no barrier)
    if (tid < 32) {
      float gi = gb[0][tid] + cbias[0];
      float gf = gb[1][tid] + cbias[1];
      float gg = gb[2][tid] + cbias[2];
      float go = gb[3][tid] + cbias[3];
      float si = 1.f / (1.f + __expf(-gi));
      float sf = 1.f / (1.f + __expf(-gf));
      float so = 1.f / (1.f + __expf(-go));
      creg = sf * creg + si * tanh_fast(gg);
      float hn = so * tanh_fast(creg);
      u64 pv = ((u64)(unsigned)(t + 1) << 32) | (u64)__float_as_uint(hn);
      st_pair(&hpub[32 * w + tid], pv);
    }
    // no end barrier: next-step polls enforce ordering
  }

  // q = h_T @ q_w^T + q_b
  if (w == 0) {
    const unsigned tgt = (unsigned)T_FRAMES;
    u64 vo = 0;
    if (!dead) {
      for (int guard = 0;; ++guard) {
        vo = ld_pair(hpub + tid);
        if (__all((unsigned)(vo >> 32) == tgt)) break;
        if (guard >= POLL_MAX) { dead = 1; break; }
      }
    }
    hsf[tid] = __uint_as_float((unsigned)vo);
    __syncthreads();
    if (tid < NA) {
      float acc = qb[tid];
      for (int k = 0; k < HID; k++) acc += hsf[k] * qw[tid * HID + k];
      out[tid] = acc;
    }
  }
}

extern "C" void kernel_launch(void* const* d_in, const int* in_sizes, int n_in,
                              void* d_out, int out_size, void* d_ws, size_t ws_size,
                              hipStream_t stream) {
  const float* frames = (const float*)d_in[0];
  const float* c1w = (const float*)d_in[1];
  const float* c1b = (const float*)d_in[2];
  const float* c2w = (const float*)d_in[3];
  const float* c2b = (const float*)d_in[4];
  const float* c3w = (const float*)d_in[5];
  const float* c3b = (const float*)d_in[6];
  const float* aw1 = (const float*)d_in[7];
  const float* ab1 = (const float*)d_in[8];
  const float* aw2 = (const float*)d_in[9];
  const float* ab2 = (const float*)d_in[10];
  const float* wih = (const float*)d_in[11];
  const float* whh = (const float*)d_in[12];
  const float* bih = (const float*)d_in[13];
  const float* bhh = (const float*)d_in[14];
  const float* qw  = (const float*)d_in[15];
  const float* qb  = (const float*)d_in[16];

  char* ws = (char*)d_ws;
  float*  fm1   = (float*)(ws + OFF_FM1);
  float*  A     = (float*)(ws + OFF_FM1);   // alias: fm1 dead after conv2
  float*  fm2   = (float*)(ws + OFF_FM2);
  float*  vecs  = (float*)(ws + OFF_VECS);
  __bf16* w2b   = (__bf16*)(ws + OFF_W2B);
  __bf16* wihb  = (__bf16*)(ws + OFF_WIHB);
  __bf16* whhb  = (__bf16*)(ws + OFF_WHHB);
  float*  w1t   = (float*)(ws + OFF_W1T);
  u64* hpub = (u64*)(ws + OFF_HPUB);   // aliases fm2 (dead after conv3)
  u64* cpub = (u64*)(ws + OFF_CPUB);

  prep_weights<<<256, 256, 0, stream>>>(aw2, wih, whh, aw1, w2b, wihb, whhb, w1t);
  conv1_k<<<102400, 256, 0, stream>>>(frames, c1w, c1b, fm1);
  conv2_k<<<T_FRAMES, 256, 0, stream>>>(fm1, c2w, c2b, fm2);
  conv3_k<<<T_FRAMES, 256, 0, stream>>>(fm2, c3w, c3b, vecs);
  aprep_k<<<T_FRAMES, 256, 0, stream>>>(vecs, w1t, ab1, A);
  init_comm<<<4, 256, 0, stream>>>(hpub, cpub);  // after conv3: comm aliases fm2
  scan_k<<<NWG, 256, 0, stream>>>(A, vecs, w2b, wihb, whhb, ab2, bih, bhh, qw, qb,
                                  hpub, cpub, (float*)d_out);
}

// Round 6
// 19558.455 us; speedup vs baseline: 5.5032x; 1.0203x over previous
//
#include <hip/hip_runtime.h>
#include <hip/hip_bf16.h>
#include <math.h>

// DARQN: conv×3 -> per-step additive attention + LSTM scan (T=2048) -> q head.
// R6: hybrid transport. Detection = 1 advisory 4B sentinel/producer (cheap
// polling, few lines/threads — R2's win). Payload = tagged 8B pairs loaded
// ONCE after detect, self-validating via per-pair tags (retry-on-stale) — so
// producers need no vmcnt drain / release / post-barrier (R5's win, without
// R5's poll-storm). h publish is single-wave program-order, zero barriers.

#define T_FRAMES 2048
#define NI 49
#define HID 256
#define NA 18
#define NWG 8
#define POLL_MAX 1000000
#define RETRY_MAX 100000

typedef __bf16 v8bf __attribute__((ext_vector_type(8)));
typedef float v4f __attribute__((ext_vector_type(4)));
typedef unsigned long long u64;

// ---------------- workspace layout (bytes) ----------------
static constexpr size_t OFF_FM1   = 0;                  // fm1 [2048,32,20,20] f32; reused for A [2048,49,256] f32
static constexpr size_t OFF_FM2   = 104857600;          // fm2 [2048,64,9,9] f32; reused for comm block
static constexpr size_t OFF_VECS  = 147324928;          // vecs [2048,49,256] f32
static constexpr size_t OFF_W2B   = 250085376;          // bf16 256*256
static constexpr size_t OFF_WIHB  = OFF_W2B  + 131072;  // bf16 1024*256
static constexpr size_t OFF_WHHB  = OFF_WIHB + 524288;  // bf16 1024*256
static constexpr size_t OFF_W1T   = OFF_WHHB + 524288;  // f32 256*256
// comm block aliases fm2 region (valid after conv3 consumed fm2):
static constexpr size_t OFF_HPUB  = OFF_FM2;            // u64[256]  (f32 h | tag)
static constexpr size_t OFF_CPUB  = OFF_FM2 + 2048;     // u64[8*128] (2xbf16 | tag)
static constexpr size_t OFF_SENT  = OFF_FM2 + 10240;    // u32[8*32] sentinel lines

__device__ __forceinline__ u64 ld_pair(const u64* p) {
  return __hip_atomic_load(p, __ATOMIC_RELAXED, __HIP_MEMORY_SCOPE_AGENT);
}
__device__ __forceinline__ void st_pair(u64* p, u64 v) {
  __hip_atomic_store(p, v, __ATOMIC_RELAXED, __HIP_MEMORY_SCOPE_AGENT);
}
__device__ __forceinline__ unsigned ld_sen(const unsigned* p) {
  return __hip_atomic_load(p, __ATOMIC_RELAXED, __HIP_MEMORY_SCOPE_AGENT);
}
__device__ __forceinline__ void st_sen(unsigned* p, unsigned v) {
  __hip_atomic_store(p, v, __ATOMIC_RELAXED, __HIP_MEMORY_SCOPE_AGENT);
}

// advisory sentinel gate: 8 lanes poll 8 producer lines; bounded; dead-latch
__device__ __forceinline__ void poll_sen(const unsigned* sen, int lane, unsigned tgt, int* dead) {
  if (*dead) return;
  const unsigned* fp = sen + ((lane < NWG) ? lane : (NWG - 1)) * 32;
  for (int g = 0;; ++g) {
    unsigned fv = ld_sen(fp);
    if (lane >= NWG) fv = tgt;
    if (__all(fv >= tgt)) return;
    if (g >= POLL_MAX) { *dead = 1; return; }
  }
}

// ---------------- weight prep ----------------
__global__ void prep_weights(const float* __restrict__ w2, const float* __restrict__ wih,
                             const float* __restrict__ whh, const float* __restrict__ w1,
                             __bf16* w2b, __bf16* wihb, __bf16* whhb, float* w1t) {
  int idx = blockIdx.x * 256 + threadIdx.x;
  int stride = gridDim.x * 256;
  for (int i = idx; i < 65536; i += stride) w2b[i] = (__bf16)w2[i];
  for (int i = idx; i < 262144; i += stride) wihb[i] = (__bf16)wih[i];
  for (int i = idx; i < 262144; i += stride) whhb[i] = (__bf16)whh[i];
  for (int i = idx; i < 65536; i += stride) {
    int r = i >> 8, c = i & 255;
    w1t[c * 256 + r] = w1[i];
  }
}

// ---------------- conv1: [T,1,84,84] -> [T,32,20,20], k8 s4 ----------------
__global__ void conv1_k(const float* __restrict__ x, const float* __restrict__ w,
                        const float* __restrict__ b, float* __restrict__ y) {
  int idx = blockIdx.x * 256 + threadIdx.x;
  if (idx >= T_FRAMES * 32 * 20 * 20) return;
  int xx = idx % 20, yy = (idx / 20) % 20, o = (idx / 400) % 32, t = idx / 12800;
  const float* xp = x + t * 7056 + yy * 4 * 84 + xx * 4;
  const float* wp = w + o * 64;
  float acc = b[o];
  #pragma unroll
  for (int ky = 0; ky < 8; ky++)
    #pragma unroll
    for (int kx = 0; kx < 8; kx++)
      acc += xp[ky * 84 + kx] * wp[ky * 8 + kx];
  y[idx] = fmaxf(acc, 0.f);
}

// ---------------- conv2: [T,32,20,20] -> [T,64,9,9], k4 s2 ----------------
__global__ __launch_bounds__(256) void conv2_k(const float* __restrict__ fm1, const float* __restrict__ w,
                                               const float* __restrict__ b, float* __restrict__ fm2) {
  __shared__ float xs[32 * 400];
  int t = blockIdx.x, tid = threadIdx.x;
  for (int i = tid; i < 12800; i += 256) xs[i] = fm1[t * 12800 + i];
  __syncthreads();
  int o = tid >> 2, q = tid & 3;
  int p0 = q * 21, p1 = (p0 + 21 < 81) ? p0 + 21 : 81;
  int ob[21];
  #pragma unroll
  for (int i2 = 0; i2 < 21; i2++) {
    int p = p0 + i2; if (p > 80) p = 80;
    int yy = p / 9, xx2 = p - yy * 9;
    ob[i2] = yy * 40 + xx2 * 2;
  }
  float acc[21];
  #pragma unroll
  for (int i2 = 0; i2 < 21; i2++) acc[i2] = 0.f;
  for (int c = 0; c < 32; c++) {
    int cbase = c * 400;
    for (int ky = 0; ky < 4; ky++)
      for (int kx = 0; kx < 4; kx++) {
        float wgt = w[((o * 32 + c) * 4 + ky) * 4 + kx];
        int kyo = ky * 20 + kx;
        #pragma unroll
        for (int i2 = 0; i2 < 21; i2++)
          acc[i2] += wgt * xs[cbase + ob[i2] + kyo];
      }
  }
  float bo = b[o];
  #pragma unroll
  for (int i2 = 0; i2 < 21; i2++) {
    int p = p0 + i2;
    if (p < p1) fm2[t * 5184 + o * 81 + p] = fmaxf(acc[i2] + bo, 0.f);
  }
}

// ---------------- conv3: [T,64,9,9] -> vecs [T,49,256], k3 s1 ----------------
__global__ __launch_bounds__(256) void conv3_k(const float* __restrict__ fm2, const float* __restrict__ w,
                                               const float* __restrict__ b, float* __restrict__ vecs) {
  __shared__ float xs[64 * 81];
  __shared__ float ws4[256][37];
  int t = blockIdx.x, tid = threadIdx.x;
  for (int i = tid; i < 64 * 81; i += 256) xs[i] = fm2[t * 5184 + i];
  float acc[49];
  #pragma unroll
  for (int i = 0; i < 49; i++) acc[i] = 0.f;
  for (int c0 = 0; c0 < 64; c0 += 4) {
    __syncthreads();
    for (int i = tid; i < 256 * 36; i += 256) {
      int oo = i / 36, j = i - oo * 36;
      ws4[oo][j] = w[oo * 576 + c0 * 9 + j];
    }
    __syncthreads();
    for (int cc = 0; cc < 4; cc++)
      for (int ky = 0; ky < 3; ky++)
        for (int kx = 0; kx < 3; kx++) {
          float wgt = ws4[tid][cc * 9 + ky * 3 + kx];
          const float* xp = &xs[(c0 + cc) * 81 + ky * 9 + kx];
          #pragma unroll
          for (int yy = 0; yy < 7; yy++)
            #pragma unroll
            for (int xx = 0; xx < 7; xx++)
              acc[yy * 7 + xx] += wgt * xp[yy * 9 + xx];
        }
  }
  float bo = b[tid];
  for (int i = 0; i < 49; i++)
    vecs[(t * 49 + i) * 256 + tid] = fmaxf(acc[i] + bo, 0.f);
}

// ---------------- A[t,i,:] = vecs[t,i,:] @ W1^T + b1 ----------------
__global__ __launch_bounds__(256) void aprep_k(const float* __restrict__ vecs, const float* __restrict__ w1t,
                                               const float* __restrict__ b1, float* __restrict__ A) {
  __shared__ float vs[49][256];
  int t = blockIdx.x, tid = threadIdx.x;
  for (int i = tid; i < 49 * 256; i += 256) vs[i >> 8][i & 255] = vecs[t * 12544 + i];
  __syncthreads();
  float acc[49];
  #pragma unroll
  for (int i = 0; i < 49; i++) acc[i] = 0.f;
  for (int k = 0; k < 256; k++) {
    float wgt = w1t[k * 256 + tid];
    #pragma unroll
    for (int i = 0; i < 49; i++) acc[i] += vs[i][k] * wgt;
  }
  float bb = b1[tid];
  for (int i = 0; i < 49; i++) A[(t * 49 + i) * 256 + tid] = acc[i] + bb;
}

// ---------------- init comm (after conv3: aliases fm2) ----------------
__global__ void init_comm(u64* hpub, u64* cpub, unsigned* sen) {
  int idx = threadIdx.x;
  if (idx < 256) hpub[idx] = 0ull;
  for (int i = idx; i < NWG * 128; i += 256) cpub[i] = 0ull;
  if (idx < NWG * 32) sen[idx] = 0u;
}

__device__ __forceinline__ float tanh_fast(float x) {
  float e = __expf(2.f * x);
  return 1.f - 2.f / (e + 1.f);
}

// ---------------- sequential scan: 8 WGs, sentinel + tagged-pair transport ----------------
__global__ __launch_bounds__(256, 1) void scan_k(
    const float* __restrict__ A, const float* __restrict__ vecs,
    const __bf16* __restrict__ w2b, const __bf16* __restrict__ wihb, const __bf16* __restrict__ whhb,
    const float* __restrict__ b2g, const float* __restrict__ bihg, const float* __restrict__ bhhg,
    const float* __restrict__ qw, const float* __restrict__ qb,
    u64* hpub, u64* cpub, unsigned* sen, float* out) {
  __shared__ __bf16 Ss[16][264];   // s rows bf16, padded
  __shared__ float hs[HID];        // f32 h
  __shared__ __bf16 hbf[HID];      // bf16 h for the Whh A-frag
  __shared__ float Wt[8][HID];     // logits / softmax rows
  __shared__ float cxp[8][HID];    // per-row ctx products
  __shared__ float b2s[HID];
  __shared__ float gb[4][32];

  const int w = blockIdx.x;
  const int tid = threadIdx.x;
  const int lane = tid & 63;
  const int wv = tid >> 6;          // wave 0..3 (= LSTM gate id)
  const int quad = lane >> 4;
  const int l15 = lane & 15;
  const int r0 = 6 * w;
  const int nr = (w < 7) ? 6 : 7;   // 7*6 + 7 = 49
  const int prow = tid >> 5;        // 0..7 staging row
  const int pcol = (tid & 31) * 8;  // 8 contiguous cols
  int dead = 0;                     // timeout latch: degrade loudly, never hang

  for (int i = tid; i < 16 * 264; i += 256) (&Ss[0][0])[i] = (__bf16)0.f;
  for (int i = tid; i < 8 * HID; i += 256) (&cxp[0][0])[i] = 0.f;
  b2s[tid] = b2g[tid];
  hs[tid] = 0.f;
  hbf[tid] = (__bf16)0.f;
  float cbias[4];
  if (tid < 32) {
    #pragma unroll
    for (int g = 0; g < 4; g++) {
      int row = 256 * g + 32 * w + tid;
      cbias[g] = bihg[row] + bhhg[row];
    }
  }
  float creg = 0.f;  // cell state: tid<32 owns dim 32*w+tid

  // ---- register-resident MFMA B-fragments ----
  v8bf BW2[4][8];  // attention: wave wv owns logit cols wv*64 + ntl*16 + l15
  #pragma unroll
  for (int ntl = 0; ntl < 4; ntl++) {
    const int row = wv * 64 + ntl * 16 + l15;
    #pragma unroll
    for (int k = 0; k < 8; k++)
      BW2[ntl][k] = *(const v8bf*)(w2b + row * 256 + k * 32 + quad * 8);
  }
  v8bf BIH[2][8], BHH[2][8];  // LSTM: gate wv, dims 32*w + nt*16 + l15
  #pragma unroll
  for (int nt = 0; nt < 2; nt++) {
    const int row = 256 * wv + 32 * w + nt * 16 + l15;
    #pragma unroll
    for (int k = 0; k < 8; k++) {
      BIH[nt][k] = *(const v8bf*)(wihb + row * 256 + k * 32 + quad * 8);
      BHH[nt][k] = *(const v8bf*)(whhb + row * 256 + k * 32 + quad * 8);
    }
  }
  __syncthreads();

  for (int t = 0; t < T_FRAMES; t++) {
    // issue this step's A/vecs loads (fly during the h wait)
    int rr = r0 + prow; if (rr > 48) rr = 48;
    const float* Ap = A + ((long)t * NI + rr) * HID + pcol;
    const float* Vp = vecs + ((long)t * NI + rr) * HID + pcol;
    const float4 a40 = *(const float4*)(Ap);
    const float4 a41 = *(const float4*)(Ap + 4);
    const float4 v40 = *(const float4*)(Vp);
    const float4 v41 = *(const float4*)(Vp + 4);

    if (t > 0) {  // ---- h_t arrival: sentinel gate, then ONE self-validating bulk load ----
      if (wv == 0) {
        poll_sen(sen, lane, 2u * (unsigned)t, &dead);  // h sentinel = 2t
        u64 hv[4];
        #pragma unroll
        for (int i = 0; i < 4; i++) hv[i] = 0;
        if (!dead) {
          for (int g = 0;; ++g) {
            #pragma unroll
            for (int i = 0; i < 4; i++) hv[i] = ld_pair(hpub + lane + 64 * i);
            unsigned ok = 1;
            #pragma unroll
            for (int i = 0; i < 4; i++) ok &= ((unsigned)(hv[i] >> 32) == (unsigned)t);
            if (__all(ok)) break;
            if (g >= RETRY_MAX) { dead = 1; break; }
          }
        }
        #pragma unroll
        for (int i = 0; i < 4; i++) {
          float hval = __uint_as_float((unsigned)hv[i]);
          hs[lane + 64 * i] = hval;
          hbf[lane + 64 * i] = (__bf16)hval;
        }
      }
      __syncthreads();  // B1: h in LDS
    }

    // stage s = tanh(A + h) as bf16 (rows >= nr stay zero)
    if (prow < nr) {
      const float* hp = &hs[pcol];
      v8bf sv;
      sv[0] = (__bf16)tanh_fast(a40.x + hp[0]);
      sv[1] = (__bf16)tanh_fast(a40.y + hp[1]);
      sv[2] = (__bf16)tanh_fast(a40.z + hp[2]);
      sv[3] = (__bf16)tanh_fast(a40.w + hp[3]);
      sv[4] = (__bf16)tanh_fast(a41.x + hp[4]);
      sv[5] = (__bf16)tanh_fast(a41.y + hp[5]);
      sv[6] = (__bf16)tanh_fast(a41.z + hp[6]);
      sv[7] = (__bf16)tanh_fast(a41.w + hp[7]);
      *(v8bf*)&Ss[prow][pcol] = sv;
    }
    __syncthreads();  // B2

    // logits = s @ W2^T + b2 (rows 0..7 valid)
    v4f acc[4];
    #pragma unroll
    for (int ntl = 0; ntl < 4; ntl++) acc[ntl] = (v4f){0.f, 0.f, 0.f, 0.f};
    #pragma unroll
    for (int k = 0; k < 8; k++) {
      const v8bf av = *(const v8bf*)&Ss[l15][k * 32 + quad * 8];
      #pragma unroll
      for (int ntl = 0; ntl < 4; ntl++)
        acc[ntl] = __builtin_amdgcn_mfma_f32_16x16x32_bf16(av, BW2[ntl][k], acc[ntl], 0, 0, 0);
    }
    if (quad < 2) {
      #pragma unroll
      for (int ntl = 0; ntl < 4; ntl++) {
        const int col = wv * 64 + ntl * 16 + l15;
        const float bb = b2s[col];
        #pragma unroll
        for (int reg = 0; reg < 4; reg++)
          Wt[quad * 4 + reg][col] = acc[ntl][reg] + bb;
      }
    }
    __syncthreads();  // B3

    // softmax + ctx products (row = prow)
    if (prow < nr) {
      float x[8];
      *(float4*)&x[0] = *(const float4*)&Wt[prow][pcol];
      *(float4*)&x[4] = *(const float4*)&Wt[prow][pcol + 4];
      float m = x[0];
      #pragma unroll
      for (int i = 1; i < 8; i++) m = fmaxf(m, x[i]);
      #pragma unroll
      for (int off = 16; off; off >>= 1) m = fmaxf(m, __shfl_xor(m, off, 64));
      float e[8], sm = 0.f;
      #pragma unroll
      for (int i = 0; i < 8; i++) { e[i] = __expf(x[i] - m); sm += e[i]; }
      #pragma unroll
      for (int off = 16; off; off >>= 1) sm += __shfl_xor(sm, off, 64);
      const float inv = 1.f / sm;
      cxp[prow][pcol + 0] = e[0] * inv * v40.x;
      cxp[prow][pcol + 1] = e[1] * inv * v40.y;
      cxp[prow][pcol + 2] = e[2] * inv * v40.z;
      cxp[prow][pcol + 3] = e[3] * inv * v40.w;
      cxp[prow][pcol + 4] = e[4] * inv * v41.x;
      cxp[prow][pcol + 5] = e[5] * inv * v41.y;
      cxp[prow][pcol + 6] = e[6] * inv * v41.z;
      cxp[prow][pcol + 7] = e[7] * inv * v41.w;
    }
    __syncthreads();  // B5

    // channel sum of my rows -> tagged pairs -> raw barrier -> advisory sentinel
    float cp = 0.f;
    #pragma unroll
    for (int r = 0; r < 8; r++) cp += cxp[r][tid];
    float cpo = __shfl_xor(cp, 1, 64);
    if ((tid & 1) == 0) {
      union { __bf16 b; unsigned short s; } lo, hi;
      lo.b = (__bf16)cp; hi.b = (__bf16)cpo;
      unsigned dat = ((unsigned)hi.s << 16) | (unsigned)lo.s;
      st_pair(&cpub[w * 128 + (tid >> 1)], ((u64)(unsigned)(t + 1) << 32) | (u64)dat);
    }
    // raw s_barrier: all stores ISSUED (no vmcnt drain — tags self-validate)
    asm volatile("s_barrier" ::: "memory");
    if (tid == 0) st_sen(&sen[w * 32], 2u * (unsigned)t + 1u);

    // h @ Whh^T chain (overlaps ctx-pair flight)
    v4f gacc[2];
    gacc[0] = (v4f){0.f, 0.f, 0.f, 0.f};
    gacc[1] = (v4f){0.f, 0.f, 0.f, 0.f};
    #pragma unroll
    for (int k = 0; k < 8; k++) {
      v8bf hf;
      #pragma unroll
      for (int z = 0; z < 8; z++) hf[z] = (__bf16)0.f;
      if (l15 == 0) hf = *(const v8bf*)&hbf[k * 32 + quad * 8];
      gacc[0] = __builtin_amdgcn_mfma_f32_16x16x32_bf16(hf, BHH[0][k], gacc[0], 0, 0, 0);
      gacc[1] = __builtin_amdgcn_mfma_f32_16x16x32_bf16(hf, BHH[1][k], gacc[1], 0, 0, 0);
    }

    // ---- ctx arrival: sentinel gate (all waves), ONE self-validating bulk load ----
    poll_sen(sen, lane, 2u * (unsigned)t + 1u, &dead);
    u64 cv[32];
    #pragma unroll
    for (int i = 0; i < 32; i++) cv[i] = 0;
    {
      const u64* cb = cpub + (l15 & 7) * 128 + quad * 4;
      if (!dead) {
        for (int g = 0;; ++g) {
          #pragma unroll
          for (int k = 0; k < 8; k++)
            #pragma unroll
            for (int i = 0; i < 4; i++)
              cv[k * 4 + i] = ld_pair(cb + k * 16 + i);
          unsigned ok = 1;
          #pragma unroll
          for (int i = 0; i < 32; i++) ok &= ((unsigned)(cv[i] >> 32) == (unsigned)(t + 1));
          if (__all(ok)) break;
          if (g >= RETRY_MAX) { dead = 1; break; }
        }
      }
    }
    const bool zrow = (l15 >= 8);
    #pragma unroll
    for (int k = 0; k < 8; k++) {
      union { unsigned u[4]; v8bf v; } pf;
      #pragma unroll
      for (int i = 0; i < 4; i++)
        pf.u[i] = zrow ? 0u : (unsigned)cv[k * 4 + i];
      gacc[0] = __builtin_amdgcn_mfma_f32_16x16x32_bf16(pf.v, BIH[0][k], gacc[0], 0, 0, 0);
      gacc[1] = __builtin_amdgcn_mfma_f32_16x16x32_bf16(pf.v, BIH[1][k], gacc[1], 0, 0, 0);
    }
    // reduce over P rows (D rows = quad*4+reg) -> per-col gate pre-activation
    #pragma unroll
    for (int nt = 0; nt < 2; nt++) {
      float tot = gacc[nt][0] + gacc[nt][1] + gacc[nt][2] + gacc[nt][3];
      tot += __shfl_xor(tot, 16, 64);
      tot += __shfl_xor(tot, 32, 64);
      if (lane < 16) gb[wv][nt * 16 + lane] = tot;
    }
    __syncthreads();  // B7

    // cell update; publish h pairs + sentinel (single-wave program order, no barrier)
    if (tid < 32) {
      float gi = gb[0][tid] + cbias[0];
      float gf = gb[1][tid] + cbias[1];
      float gg = gb[2][tid] + cbias[2];
      float go = gb[3][tid] + cbias[3];
      float si = 1.f / (1.f + __expf(-gi));
      float sf = 1.f / (1.f + __expf(-gf));
      float so = 1.f / (1.f + __expf(-go));
      creg = sf * creg + si * tanh_fast(gg);
      float hn = so * tanh_fast(creg);
      st_pair(&hpub[32 * w + tid], ((u64)(unsigned)(t + 1) << 32) | (u64)__float_as_uint(hn));
    }
    if (tid == 0) st_sen(&sen[w * 32], 2u * (unsigned)t + 2u);
  }

  // q = h_T @ q_w^T + q_b
  if (w == 0) {
    if (wv == 0) {
      poll_sen(sen, lane, 2u * (unsigned)T_FRAMES, &dead);
      u64 hv[4];
      #pragma unroll
      for (int i = 0; i < 4; i++) hv[i] = 0;
      if (!dead) {
        for (int g = 0;; ++g) {
          #pragma unroll
          for (int i = 0; i < 4; i++) hv[i] = ld_pair(hpub + lane + 64 * i);
          unsigned ok = 1;
          #pragma unroll
          for (int i = 0; i < 4; i++) ok &= ((unsigned)(hv[i] >> 32) == (unsigned)T_FRAMES);
          if (__all(ok)) break;
          if (g >= RETRY_MAX) { dead = 1; break; }
        }
      }
      #pragma unroll
      for (int i = 0; i < 4; i++) hs[lane + 64 * i] = __uint_as_float((unsigned)hv[i]);
    }
    __syncthreads();
    if (tid < NA) {
      float acc = qb[tid];
      for (int k = 0; k < HID; k++) acc += hs[k] * qw[tid * HID + k];
      out[tid] = acc;
    }
  }
}

extern "C" void kernel_launch(void* const* d_in, const int* in_sizes, int n_in,
                              void* d_out, int out_size, void* d_ws, size_t ws_size,
                              hipStream_t stream) {
  const float* frames = (const float*)d_in[0];
  const float* c1w = (const float*)d_in[1];
  const float* c1b = (const float*)d_in[2];
  const float* c2w = (const float*)d_in[3];
  const float* c2b = (const float*)d_in[4];
  const float* c3w = (const float*)d_in[5];
  const float* c3b = (const float*)d_in[6];
  const float* aw1 = (const float*)d_in[7];
  const float* ab1 = (const float*)d_in[8];
  const float* aw2 = (const float*)d_in[9];
  const float* ab2 = (const float*)d_in[10];
  const float* wih = (const float*)d_in[11];
  const float* whh = (const float*)d_in[12];
  const float* bih = (const float*)d_in[13];
  const float* bhh = (const float*)d_in[14];
  const float* qw  = (const float*)d_in[15];
  const float* qb  = (const float*)d_in[16];

  char* ws = (char*)d_ws;
  float*  fm1   = (float*)(ws + OFF_FM1);
  float*  A     = (float*)(ws + OFF_FM1);   // alias: fm1 dead after conv2
  float*  fm2   = (float*)(ws + OFF_FM2);
  float*  vecs  = (float*)(ws + OFF_VECS);
  __bf16* w2b   = (__bf16*)(ws + OFF_W2B);
  __bf16* wihb  = (__bf16*)(ws + OFF_WIHB);
  __bf16* whhb  = (__bf16*)(ws + OFF_WHHB);
  float*  w1t   = (float*)(ws + OFF_W1T);
  u64* hpub = (u64*)(ws + OFF_HPUB);   // aliases fm2 (dead after conv3)
  u64* cpub = (u64*)(ws + OFF_CPUB);
  unsigned* sen = (unsigned*)(ws + OFF_SENT);

  prep_weights<<<256, 256, 0, stream>>>(aw2, wih, whh, aw1, w2b, wihb, whhb, w1t);
  conv1_k<<<102400, 256, 0, stream>>>(frames, c1w, c1b, fm1);
  conv2_k<<<T_FRAMES, 256, 0, stream>>>(fm1, c2w, c2b, fm2);
  conv3_k<<<T_FRAMES, 256, 0, stream>>>(fm2, c3w, c3b, vecs);
  aprep_k<<<T_FRAMES, 256, 0, stream>>>(vecs, w1t, ab1, A);
  init_comm<<<1, 256, 0, stream>>>(hpub, cpub, sen);  // after conv3: comm aliases fm2
  scan_k<<<NWG, 256, 0, stream>>>(A, vecs, w2b, wihb, whhb, ab2, bih, bhh, qw, qb,
                                  hpub, cpub, sen, (float*)d_out);
}